// Round 1
// baseline (3380.909 us; speedup 1.0000x reference)
//
#include <hip/hip_runtime.h>

#define IN_DIM 784
#define HID 128
#define NSTEP 16
#define BATCH 16384

// ws float layout (all fp32):
constexpr int W0T_OFF = 0;                    // W0t[k*128+j] = W0[j][k]*r0   (784x128)
constexpr int W1T_OFF = W0T_OFF + IN_DIM*HID; // 100352: W1t (128x128)
constexpr int W2T_OFF = W1T_OFF + HID*HID;    // 116736: W2t (128x128)
constexpr int W3T_OFF = W2T_OFF + HID*HID;    // 133120: W3t[k*784+o] = W3[o][k]*r3 (128x784)
constexpr int B0_OFF  = W3T_OFF + HID*IN_DIM; // 233472
constexpr int B1_OFF  = B0_OFF + HID;
constexpr int B2_OFF  = B1_OFF + HID;
constexpr int B3_OFF  = B2_OFF + HID;
constexpr int WS_FLOATS = B3_OFF + IN_DIM;    // 234640 floats = 938 KB

__global__ __launch_bounds__(256) void prep_kernel(
    const float* __restrict__ W0, const float* __restrict__ b0,
    const float* __restrict__ W1, const float* __restrict__ b1,
    const float* __restrict__ W2, const float* __restrict__ b2,
    const float* __restrict__ W3, const float* __restrict__ b3,
    const float* __restrict__ ib0, const float* __restrict__ ob0,
    const float* __restrict__ ib1, const float* __restrict__ ob1,
    const float* __restrict__ ib2, const float* __restrict__ ob2,
    const float* __restrict__ ib3, const float* __restrict__ ob3,
    float* __restrict__ ws)
{
    int idx = blockIdx.x * 256 + threadIdx.x;
    if (idx >= WS_FLOATS) return;
    float r0 = (ib0[1] - ib0[0]) / (ob0[1] - ob0[0]);
    float r1 = (ib1[1] - ib1[0]) / (ob1[1] - ob1[0]);
    float r2 = (ib2[1] - ib2[0]) / (ob2[1] - ob2[0]);
    float r3 = (ib3[1] - ib3[0]) / (ob3[1] - ob3[0]);
    if (idx < W1T_OFF) {
        int t = idx;            int k = t >> 7, j = t & 127;
        ws[idx] = W0[j * IN_DIM + k] * r0;
    } else if (idx < W2T_OFF) {
        int t = idx - W1T_OFF;  int k = t >> 7, j = t & 127;
        ws[idx] = W1[j * HID + k] * r1;
    } else if (idx < W3T_OFF) {
        int t = idx - W2T_OFF;  int k = t >> 7, j = t & 127;
        ws[idx] = W2[j * HID + k] * r2;
    } else if (idx < B0_OFF) {
        int t = idx - W3T_OFF;  int k = t / IN_DIM, o = t % IN_DIM;
        ws[idx] = W3[o * HID + k] * r3;
    } else if (idx < B1_OFF) ws[idx] = b0[idx - B0_OFF] * r0;
    else if (idx < B2_OFF)   ws[idx] = b1[idx - B1_OFF] * r1;
    else if (idx < B3_OFF)   ws[idx] = b2[idx - B2_OFF] * r2;
    else                     ws[idx] = b3[idx - B3_OFF] * r3;
}

__global__ __launch_bounds__(256) void snn_main(
    const float* __restrict__ feat,
    const float* __restrict__ ws,
    const float* __restrict__ ib0,
    const float* __restrict__ ob3,
    float* __restrict__ out)
{
    const int lane = threadIdx.x & 63;
    const int sample = blockIdx.x * 4 + (threadIdx.x >> 6);

    const float* W0t = ws + W0T_OFF;
    const float* W1t = ws + W1T_OFF;
    const float* W2t = ws + W2T_OFF;
    const float* W3t = ws + W3T_OFF;

    // ---- digitize features (bit-exact vs jnp.digitize on loaded edges) ----
    float edge[16];
#pragma unroll
    for (int e = 0; e < 16; ++e) edge[e] = ib0[e + 1];

    int m[13];
    {
        const float* frow = feat + (size_t)sample * IN_DIM;
#pragma unroll
        for (int r = 0; r < 13; ++r) {
            int idx = r * 64 + lane;
            int mm = 0;
            if (idx < IN_DIM) {
                float x = frow[idx];
#pragma unroll
                for (int e = 0; e < 16; ++e) mm += (x >= edge[e]) ? 1 : 0;
            }
            m[r] = mm;
        }
    }

    // ---- persistent membrane state ----
    float2 t0 = ((const float2*)(ws + B0_OFF))[lane];   // neurons 2*lane, 2*lane+1
    float2 t1 = ((const float2*)(ws + B1_OFF))[lane];
    float2 t2 = ((const float2*)(ws + B2_OFF))[lane];
    float4 t3[4], cnt[4];                               // elems r*256 + 4*lane + c
    {
        const float4* b3v = (const float4*)(ws + B3_OFF);
#pragma unroll
        for (int r = 0; r < 3; ++r) t3[r] = b3v[r * 64 + lane];
        t3[3] = make_float4(0.f, 0.f, 0.f, 0.f);
        if (lane < 4) t3[3] = b3v[192 + lane];
#pragma unroll
        for (int r = 0; r < 4; ++r) cnt[r] = make_float4(0.f, 0.f, 0.f, 0.f);
    }

    for (int s = 1; s <= NSTEP; ++s) {
        // ---- input spikes -> layer0 ----
#pragma unroll
        for (int r = 0; r < 13; ++r) {
            int p = __mul24(s, m[r]);
            unsigned long long mk = __ballot((p & 15) < m[r]);
            while (mk) {
                int b = __builtin_ctzll(mk);
                mk &= mk - 1;
                const float2* col = (const float2*)(W0t + (r * 64 + b) * HID);
                float2 w = col[lane];
                t0.x += w.x; t0.y += w.y;
            }
        }
        // ---- layer0 spikes -> layer1 ----
        {
            bool px = (t0.x >= 1.0f), py = (t0.y >= 1.0f);
            unsigned long long mx = __ballot(px);
            unsigned long long my = __ballot(py);
            if (px) t0.x -= 1.0f;
            if (py) t0.y -= 1.0f;
            while (mx) {
                int b = __builtin_ctzll(mx); mx &= mx - 1;
                const float2* col = (const float2*)(W1t + (2 * b) * HID);
                float2 w = col[lane]; t1.x += w.x; t1.y += w.y;
            }
            while (my) {
                int b = __builtin_ctzll(my); my &= my - 1;
                const float2* col = (const float2*)(W1t + (2 * b + 1) * HID);
                float2 w = col[lane]; t1.x += w.x; t1.y += w.y;
            }
        }
        // ---- layer1 spikes -> layer2 ----
        {
            bool px = (t1.x >= 1.0f), py = (t1.y >= 1.0f);
            unsigned long long mx = __ballot(px);
            unsigned long long my = __ballot(py);
            if (px) t1.x -= 1.0f;
            if (py) t1.y -= 1.0f;
            while (mx) {
                int b = __builtin_ctzll(mx); mx &= mx - 1;
                const float2* col = (const float2*)(W2t + (2 * b) * HID);
                float2 w = col[lane]; t2.x += w.x; t2.y += w.y;
            }
            while (my) {
                int b = __builtin_ctzll(my); my &= my - 1;
                const float2* col = (const float2*)(W2t + (2 * b + 1) * HID);
                float2 w = col[lane]; t2.x += w.x; t2.y += w.y;
            }
        }
        // ---- layer2 spikes -> layer3 ----
        {
            bool px = (t2.x >= 1.0f), py = (t2.y >= 1.0f);
            unsigned long long mx = __ballot(px);
            unsigned long long my = __ballot(py);
            if (px) t2.x -= 1.0f;
            if (py) t2.y -= 1.0f;
            while (mx) {
                int b = __builtin_ctzll(mx); mx &= mx - 1;
                const float4* col = (const float4*)(W3t + (2 * b) * IN_DIM);
#pragma unroll
                for (int r = 0; r < 3; ++r) {
                    float4 w = col[r * 64 + lane];
                    t3[r].x += w.x; t3[r].y += w.y; t3[r].z += w.z; t3[r].w += w.w;
                }
                if (lane < 4) {
                    float4 w = col[192 + lane];
                    t3[3].x += w.x; t3[3].y += w.y; t3[3].z += w.z; t3[3].w += w.w;
                }
            }
            while (my) {
                int b = __builtin_ctzll(my); my &= my - 1;
                const float4* col = (const float4*)(W3t + (2 * b + 1) * IN_DIM);
#pragma unroll
                for (int r = 0; r < 3; ++r) {
                    float4 w = col[r * 64 + lane];
                    t3[r].x += w.x; t3[r].y += w.y; t3[r].z += w.z; t3[r].w += w.w;
                }
                if (lane < 4) {
                    float4 w = col[192 + lane];
                    t3[3].x += w.x; t3[3].y += w.y; t3[3].z += w.z; t3[3].w += w.w;
                }
            }
        }
        // ---- layer3 spike + output count ----
#pragma unroll
        for (int r = 0; r < 4; ++r) {
            if (t3[r].x >= 1.0f) { t3[r].x -= 1.0f; cnt[r].x += 1.0f; }
            if (t3[r].y >= 1.0f) { t3[r].y -= 1.0f; cnt[r].y += 1.0f; }
            if (t3[r].z >= 1.0f) { t3[r].z -= 1.0f; cnt[r].z += 1.0f; }
            if (t3[r].w >= 1.0f) { t3[r].w -= 1.0f; cnt[r].w += 1.0f; }
        }
        __syncthreads();   // keep the block's 4 waves roughly lockstep for L1 reuse
    }

    // ---- reconstruct: spikes * h_out3 ----
    const float h = ob3[1] - ob3[0];
    float4* orow = (float4*)(out + (size_t)sample * IN_DIM);
#pragma unroll
    for (int r = 0; r < 3; ++r)
        orow[r * 64 + lane] = make_float4(cnt[r].x * h, cnt[r].y * h, cnt[r].z * h, cnt[r].w * h);
    if (lane < 4)
        orow[192 + lane] = make_float4(cnt[3].x * h, cnt[3].y * h, cnt[3].z * h, cnt[3].w * h);
}

extern "C" void kernel_launch(void* const* d_in, const int* in_sizes, int n_in,
                              void* d_out, int out_size, void* d_ws, size_t ws_size,
                              hipStream_t stream)
{
    const float* feat = (const float*)d_in[0];
    const float* W0  = (const float*)d_in[1];
    const float* b0  = (const float*)d_in[2];
    const float* W1  = (const float*)d_in[3];
    const float* b1  = (const float*)d_in[4];
    const float* W2  = (const float*)d_in[5];
    const float* b2  = (const float*)d_in[6];
    const float* W3  = (const float*)d_in[7];
    const float* b3  = (const float*)d_in[8];
    const float* ib0 = (const float*)d_in[9];
    const float* ob0 = (const float*)d_in[10];
    const float* ib1 = (const float*)d_in[11];
    const float* ob1 = (const float*)d_in[12];
    const float* ib2 = (const float*)d_in[13];
    const float* ob2 = (const float*)d_in[14];
    const float* ib3 = (const float*)d_in[15];
    const float* ob3 = (const float*)d_in[16];
    float* ws  = (float*)d_ws;
    float* op  = (float*)d_out;

    prep_kernel<<<(WS_FLOATS + 255) / 256, 256, 0, stream>>>(
        W0, b0, W1, b1, W2, b2, W3, b3,
        ib0, ob0, ib1, ob1, ib2, ob2, ib3, ob3, ws);

    snn_main<<<BATCH / 4, 256, 0, stream>>>(feat, ws, ib0, ob3, op);
}

// Round 2
// 466.599 us; speedup vs baseline: 7.2459x; 7.2459x over previous
//
#include <hip/hip_runtime.h>

#define IN_DIM 784
#define HID 128
#define NSTEP 16
#define BATCH 16384

// ws float layout (all fp32):
constexpr int W0T_OFF = 0;                    // W0t[k*128+j] = W0[j][k]*r0   (784x128)
constexpr int W1T_OFF = W0T_OFF + IN_DIM*HID; // 100352: W1t (128x128)
constexpr int W2T_OFF = W1T_OFF + HID*HID;    // 116736: W2t (128x128)
constexpr int W3T_OFF = W2T_OFF + HID*HID;    // 133120: W3t[k*784+o] = W3[o][k]*r3 (128x784)
constexpr int B0_OFF  = W3T_OFF + HID*IN_DIM; // 233472
constexpr int B1_OFF  = B0_OFF + HID;
constexpr int B2_OFF  = B1_OFF + HID;
constexpr int B3_OFF  = B2_OFF + HID;
constexpr int WS_FLOATS = B3_OFF + IN_DIM;    // 234640 floats = 938 KB

__global__ __launch_bounds__(256) void prep_kernel(
    const float* __restrict__ W0, const float* __restrict__ b0,
    const float* __restrict__ W1, const float* __restrict__ b1,
    const float* __restrict__ W2, const float* __restrict__ b2,
    const float* __restrict__ W3, const float* __restrict__ b3,
    const float* __restrict__ ib0, const float* __restrict__ ob0,
    const float* __restrict__ ib1, const float* __restrict__ ob1,
    const float* __restrict__ ib2, const float* __restrict__ ob2,
    const float* __restrict__ ib3, const float* __restrict__ ob3,
    float* __restrict__ ws)
{
    int idx = blockIdx.x * 256 + threadIdx.x;
    if (idx >= WS_FLOATS) return;
    float r0 = (ib0[1] - ib0[0]) / (ob0[1] - ob0[0]);
    float r1 = (ib1[1] - ib1[0]) / (ob1[1] - ob1[0]);
    float r2 = (ib2[1] - ib2[0]) / (ob2[1] - ob2[0]);
    float r3 = (ib3[1] - ib3[0]) / (ob3[1] - ob3[0]);
    if (idx < W1T_OFF) {
        int t = idx;            int k = t >> 7, j = t & 127;
        ws[idx] = W0[j * IN_DIM + k] * r0;
    } else if (idx < W2T_OFF) {
        int t = idx - W1T_OFF;  int k = t >> 7, j = t & 127;
        ws[idx] = W1[j * HID + k] * r1;
    } else if (idx < W3T_OFF) {
        int t = idx - W2T_OFF;  int k = t >> 7, j = t & 127;
        ws[idx] = W2[j * HID + k] * r2;
    } else if (idx < B0_OFF) {
        int t = idx - W3T_OFF;  int k = t / IN_DIM, o = t % IN_DIM;
        ws[idx] = W3[o * HID + k] * r3;
    } else if (idx < B1_OFF) ws[idx] = b0[idx - B0_OFF] * r0;
    else if (idx < B2_OFF)   ws[idx] = b1[idx - B1_OFF] * r1;
    else if (idx < B3_OFF)   ws[idx] = b2[idx - B2_OFF] * r2;
    else                     ws[idx] = b3[idx - B3_OFF] * r3;
}

__global__ __launch_bounds__(256) void snn_main(
    const float* __restrict__ feat,
    const float* __restrict__ ws,
    const float* __restrict__ ib0,
    const float* __restrict__ ob3,
    float* __restrict__ out)
{
    const int lane = threadIdx.x & 63;
    const int sample = blockIdx.x * 4 + (threadIdx.x >> 6);

    const float* W0t = ws + W0T_OFF;
    const float* W1t = ws + W1T_OFF;
    const float* W2t = ws + W2T_OFF;
    const float* W3t = ws + W3T_OFF;

    // ---- digitize features (bit-exact vs jnp.digitize on loaded edges) ----
    float edge[16];
#pragma unroll
    for (int e = 0; e < 16; ++e) edge[e] = ib0[e + 1];

    int m[13];
    {
        const float* frow = feat + (size_t)sample * IN_DIM;
#pragma unroll
        for (int r = 0; r < 13; ++r) {
            int idx = r * 64 + lane;
            int mm = 0;
            if (idx < IN_DIM) {
                float x = frow[idx];
#pragma unroll
                for (int e = 0; e < 16; ++e) mm += (x >= edge[e]) ? 1 : 0;
            }
            m[r] = mm;
        }
    }

    // ---- build per-level bucket sums: C[mv-1] = sum of W0t columns whose pixel level == mv ----
    // Each W0 column is loaded exactly ONCE per sample (vs ~8x when done per step).
    float2 C[16];
#pragma unroll
    for (int mv = 1; mv <= 16; ++mv) {
        float2 ca = make_float2(0.f, 0.f), cb = make_float2(0.f, 0.f);
#pragma unroll
        for (int r = 0; r < 13; ++r) {
            unsigned long long mk = __ballot(m[r] == mv);
            while (mk) {
                int b0 = __builtin_ctzll(mk); mk &= mk - 1;
                float2 w0 = ((const float2*)(W0t + (unsigned)((r << 6) + b0) * HID))[lane];
                if (mk) {
                    int b1 = __builtin_ctzll(mk); mk &= mk - 1;
                    float2 w1 = ((const float2*)(W0t + (unsigned)((r << 6) + b1) * HID))[lane];
                    if (mk) {
                        int b2 = __builtin_ctzll(mk); mk &= mk - 1;
                        float2 w2 = ((const float2*)(W0t + (unsigned)((r << 6) + b2) * HID))[lane];
                        if (mk) {
                            int b3i = __builtin_ctzll(mk); mk &= mk - 1;
                            float2 w3 = ((const float2*)(W0t + (unsigned)((r << 6) + b3i) * HID))[lane];
                            cb.x += w3.x; cb.y += w3.y;
                        }
                        ca.x += w2.x; ca.y += w2.y;
                    }
                    cb.x += w1.x; cb.y += w1.y;
                }
                ca.x += w0.x; ca.y += w0.y;
            }
        }
        C[mv - 1] = make_float2(ca.x + cb.x, ca.y + cb.y);
    }

    // ---- persistent membrane state ----
    float2 t0 = ((const float2*)(ws + B0_OFF))[lane];   // neurons 2*lane, 2*lane+1
    float2 t1 = ((const float2*)(ws + B1_OFF))[lane];
    float2 t2 = ((const float2*)(ws + B2_OFF))[lane];
    float4 t3[4], cnt[4];                               // elems r*256 + 4*lane + c
    {
        const float4* b3v = (const float4*)(ws + B3_OFF);
#pragma unroll
        for (int r = 0; r < 3; ++r) t3[r] = b3v[r * 64 + lane];
        t3[3] = make_float4(0.f, 0.f, 0.f, 0.f);
        if (lane < 4) t3[3] = b3v[192 + lane];
#pragma unroll
        for (int r = 0; r < 4; ++r) cnt[r] = make_float4(0.f, 0.f, 0.f, 0.f);
    }

    for (int s = 1; s <= NSTEP; ++s) {
        // ---- input current: sum of active bucket vectors (uniform scalar branches, register-only) ----
#pragma unroll
        for (int mv = 1; mv <= 16; ++mv) {
            if (((s * mv) & 15) < mv) { t0.x += C[mv - 1].x; t0.y += C[mv - 1].y; }
        }
        // ---- layer0 spikes -> layer1 ----
        {
            bool px = (t0.x >= 1.0f), py = (t0.y >= 1.0f);
            unsigned long long mx = __ballot(px);
            unsigned long long my = __ballot(py);
            if (px) t0.x -= 1.0f;
            if (py) t0.y -= 1.0f;
            while (mx) {
                int b = __builtin_ctzll(mx); mx &= mx - 1;
                const float2* col = (const float2*)(W1t + (2 * b) * HID);
                float2 w = col[lane]; t1.x += w.x; t1.y += w.y;
            }
            while (my) {
                int b = __builtin_ctzll(my); my &= my - 1;
                const float2* col = (const float2*)(W1t + (2 * b + 1) * HID);
                float2 w = col[lane]; t1.x += w.x; t1.y += w.y;
            }
        }
        // ---- layer1 spikes -> layer2 ----
        {
            bool px = (t1.x >= 1.0f), py = (t1.y >= 1.0f);
            unsigned long long mx = __ballot(px);
            unsigned long long my = __ballot(py);
            if (px) t1.x -= 1.0f;
            if (py) t1.y -= 1.0f;
            while (mx) {
                int b = __builtin_ctzll(mx); mx &= mx - 1;
                const float2* col = (const float2*)(W2t + (2 * b) * HID);
                float2 w = col[lane]; t2.x += w.x; t2.y += w.y;
            }
            while (my) {
                int b = __builtin_ctzll(my); my &= my - 1;
                const float2* col = (const float2*)(W2t + (2 * b + 1) * HID);
                float2 w = col[lane]; t2.x += w.x; t2.y += w.y;
            }
        }
        // ---- layer2 spikes -> layer3 ----
        {
            bool px = (t2.x >= 1.0f), py = (t2.y >= 1.0f);
            unsigned long long mx = __ballot(px);
            unsigned long long my = __ballot(py);
            if (px) t2.x -= 1.0f;
            if (py) t2.y -= 1.0f;
            while (mx) {
                int b = __builtin_ctzll(mx); mx &= mx - 1;
                const float4* col = (const float4*)(W3t + (2 * b) * IN_DIM);
#pragma unroll
                for (int r = 0; r < 3; ++r) {
                    float4 w = col[r * 64 + lane];
                    t3[r].x += w.x; t3[r].y += w.y; t3[r].z += w.z; t3[r].w += w.w;
                }
                if (lane < 4) {
                    float4 w = col[192 + lane];
                    t3[3].x += w.x; t3[3].y += w.y; t3[3].z += w.z; t3[3].w += w.w;
                }
            }
            while (my) {
                int b = __builtin_ctzll(my); my &= my - 1;
                const float4* col = (const float4*)(W3t + (2 * b + 1) * IN_DIM);
#pragma unroll
                for (int r = 0; r < 3; ++r) {
                    float4 w = col[r * 64 + lane];
                    t3[r].x += w.x; t3[r].y += w.y; t3[r].z += w.z; t3[r].w += w.w;
                }
                if (lane < 4) {
                    float4 w = col[192 + lane];
                    t3[3].x += w.x; t3[3].y += w.y; t3[3].z += w.z; t3[3].w += w.w;
                }
            }
        }
        // ---- layer3 spike + output count ----
#pragma unroll
        for (int r = 0; r < 4; ++r) {
            if (t3[r].x >= 1.0f) { t3[r].x -= 1.0f; cnt[r].x += 1.0f; }
            if (t3[r].y >= 1.0f) { t3[r].y -= 1.0f; cnt[r].y += 1.0f; }
            if (t3[r].z >= 1.0f) { t3[r].z -= 1.0f; cnt[r].z += 1.0f; }
            if (t3[r].w >= 1.0f) { t3[r].w -= 1.0f; cnt[r].w += 1.0f; }
        }
    }

    // ---- reconstruct: spikes * h_out3 ----
    const float h = ob3[1] - ob3[0];
    float4* orow = (float4*)(out + (size_t)sample * IN_DIM);
#pragma unroll
    for (int r = 0; r < 3; ++r)
        orow[r * 64 + lane] = make_float4(cnt[r].x * h, cnt[r].y * h, cnt[r].z * h, cnt[r].w * h);
    if (lane < 4)
        orow[192 + lane] = make_float4(cnt[3].x * h, cnt[3].y * h, cnt[3].z * h, cnt[3].w * h);
}

extern "C" void kernel_launch(void* const* d_in, const int* in_sizes, int n_in,
                              void* d_out, int out_size, void* d_ws, size_t ws_size,
                              hipStream_t stream)
{
    const float* feat = (const float*)d_in[0];
    const float* W0  = (const float*)d_in[1];
    const float* b0  = (const float*)d_in[2];
    const float* W1  = (const float*)d_in[3];
    const float* b1  = (const float*)d_in[4];
    const float* W2  = (const float*)d_in[5];
    const float* b2  = (const float*)d_in[6];
    const float* W3  = (const float*)d_in[7];
    const float* b3  = (const float*)d_in[8];
    const float* ib0 = (const float*)d_in[9];
    const float* ob0 = (const float*)d_in[10];
    const float* ib1 = (const float*)d_in[11];
    const float* ob1 = (const float*)d_in[12];
    const float* ib2 = (const float*)d_in[13];
    const float* ob2 = (const float*)d_in[14];
    const float* ib3 = (const float*)d_in[15];
    const float* ob3 = (const float*)d_in[16];
    float* ws  = (float*)d_ws;
    float* op  = (float*)d_out;

    prep_kernel<<<(WS_FLOATS + 255) / 256, 256, 0, stream>>>(
        W0, b0, W1, b1, W2, b2, W3, b3,
        ib0, ob0, ib1, ob1, ib2, ob2, ib3, ob3, ws);

    snn_main<<<BATCH / 4, 256, 0, stream>>>(feat, ws, ib0, ob3, op);
}

// Round 3
// 436.855 us; speedup vs baseline: 7.7392x; 1.0681x over previous
//
#include <hip/hip_runtime.h>

#define IN_DIM 784
#define HID 128
#define NSTEP 16
#define BATCH 16384

// ws float layout (all fp32):
constexpr int W0T_OFF = 0;                    // W0t[k*128+j] = W0[j][k]*r0   (784x128)
constexpr int W1T_OFF = W0T_OFF + IN_DIM*HID; // 100352: W1t (128x128)
constexpr int W2T_OFF = W1T_OFF + HID*HID;    // 116736: W2t (128x128)
constexpr int W3T_OFF = W2T_OFF + HID*HID;    // 133120: W3t[k*784+o] = W3[o][k]*r3 (128x784)
constexpr int B0_OFF  = W3T_OFF + HID*IN_DIM; // 233472
constexpr int B1_OFF  = B0_OFF + HID;
constexpr int B2_OFF  = B1_OFF + HID;
constexpr int B3_OFF  = B2_OFF + HID;
constexpr int WS_FLOATS = B3_OFF + IN_DIM;    // 234640 floats = 938 KB

// chunking of W0t for LDS staging
constexpr int CHUNK_COLS = 32;                // 32 cols x 128 floats = 16 KB
constexpr int CHUNK_F    = CHUNK_COLS * HID;  // 4096 floats
constexpr int NCHUNK     = 25;                // 24 full + 1 half (cols 768..783)

__global__ __launch_bounds__(256) void prep_kernel(
    const float* __restrict__ W0, const float* __restrict__ b0,
    const float* __restrict__ W1, const float* __restrict__ b1,
    const float* __restrict__ W2, const float* __restrict__ b2,
    const float* __restrict__ W3, const float* __restrict__ b3,
    const float* __restrict__ ib0, const float* __restrict__ ob0,
    const float* __restrict__ ib1, const float* __restrict__ ob1,
    const float* __restrict__ ib2, const float* __restrict__ ob2,
    const float* __restrict__ ib3, const float* __restrict__ ob3,
    float* __restrict__ ws)
{
    int idx = blockIdx.x * 256 + threadIdx.x;
    if (idx >= WS_FLOATS) return;
    float r0 = (ib0[1] - ib0[0]) / (ob0[1] - ob0[0]);
    float r1 = (ib1[1] - ib1[0]) / (ob1[1] - ob1[0]);
    float r2 = (ib2[1] - ib2[0]) / (ob2[1] - ob2[0]);
    float r3 = (ib3[1] - ib3[0]) / (ob3[1] - ob3[0]);
    if (idx < W1T_OFF) {
        int t = idx;            int k = t >> 7, j = t & 127;
        ws[idx] = W0[j * IN_DIM + k] * r0;
    } else if (idx < W2T_OFF) {
        int t = idx - W1T_OFF;  int k = t >> 7, j = t & 127;
        ws[idx] = W1[j * HID + k] * r1;
    } else if (idx < W3T_OFF) {
        int t = idx - W2T_OFF;  int k = t >> 7, j = t & 127;
        ws[idx] = W2[j * HID + k] * r2;
    } else if (idx < B0_OFF) {
        int t = idx - W3T_OFF;  int k = t / IN_DIM, o = t % IN_DIM;
        ws[idx] = W3[o * HID + k] * r3;
    } else if (idx < B1_OFF) ws[idx] = b0[idx - B0_OFF] * r0;
    else if (idx < B2_OFF)   ws[idx] = b1[idx - B1_OFF] * r1;
    else if (idx < B3_OFF)   ws[idx] = b2[idx - B2_OFF] * r2;
    else                     ws[idx] = b3[idx - B3_OFF] * r3;
}

__global__ __launch_bounds__(256) void snn_main(
    const float* __restrict__ feat,
    const float* __restrict__ ws,
    const float* __restrict__ ib0,
    const float* __restrict__ ob3,
    float* __restrict__ out)
{
    __shared__ float smem[2 * CHUNK_F];       // 32 KB double buffer

    const int tid  = threadIdx.x;
    const int lane = tid & 63;
    const int wid  = tid >> 6;
    const int sample = blockIdx.x * 4 + wid;

    const float* W0t = ws + W0T_OFF;
    const float* W1t = ws + W1T_OFF;
    const float* W2t = ws + W2T_OFF;
    const float* W3t = ws + W3T_OFF;
    const float* frow = feat + (size_t)sample * IN_DIM;

    float edge[16];
#pragma unroll
    for (int e = 0; e < 16; ++e) edge[e] = ib0[e + 1];

    // ---- stage chunk 0 ----
    {
        const float4* g4 = (const float4*)W0t;
        float4* lb = (float4*)smem;
#pragma unroll
        for (int i = 0; i < 4; ++i) lb[i * 256 + tid] = g4[i * 256 + tid];
    }
    __syncthreads();

    // ---- bucket build: C[mv-1] = sum of W0t columns whose pixel level == mv ----
    float2 C[16];
#pragma unroll
    for (int mv = 0; mv < 16; ++mv) C[mv] = make_float2(0.f, 0.f);

    for (int c = 0; c < NCHUNK; ++c) {
        // prefetch next chunk into registers (issued early; overlaps consume).
        // unconditional: for c==24 this reads into W1T region (valid memory), discarded.
        float4 rg0, rg1, rg2, rg3;
        {
            const float4* g4 = (const float4*)W0t + (size_t)(c + 1) * (CHUNK_F / 4);
            rg0 = g4[0 * 256 + tid];
            rg1 = g4[1 * 256 + tid];
            rg2 = g4[2 * 256 + tid];
            rg3 = g4[3 * 256 + tid];
        }

        // digitize this chunk's 32 columns (lanes 32-63 duplicate lanes 0-31)
        int col = c * CHUNK_COLS + (lane & 31);
        bool valid = col < IN_DIM;
        float x = frow[valid ? col : 0];
        int mm = 0;
#pragma unroll
        for (int e = 0; e < 16; ++e) mm += (x >= edge[e]) ? 1 : 0;
        if (!valid) mm = -1;

        // consume chunk c from LDS
        const float2* bufp = (const float2*)(smem + (c & 1) * CHUNK_F);
#pragma unroll
        for (int mv = 1; mv <= 16; ++mv) {
            unsigned mk = (unsigned)__ballot(mm == mv);   // low 32 bits = this chunk's cols
            float2 ca = make_float2(0.f, 0.f), cb = make_float2(0.f, 0.f);
            while (mk) {
                int b0 = __builtin_ctz(mk); mk &= mk - 1;
                float2 w0 = bufp[b0 * 64 + lane];
                if (mk) {
                    int b1 = __builtin_ctz(mk); mk &= mk - 1;
                    float2 w1 = bufp[b1 * 64 + lane];
                    if (mk) {
                        int b2 = __builtin_ctz(mk); mk &= mk - 1;
                        float2 w2 = bufp[b2 * 64 + lane];
                        if (mk) {
                            int b3i = __builtin_ctz(mk); mk &= mk - 1;
                            float2 w3 = bufp[b3i * 64 + lane];
                            cb.x += w3.x; cb.y += w3.y;
                        }
                        ca.x += w2.x; ca.y += w2.y;
                    }
                    cb.x += w1.x; cb.y += w1.y;
                }
                ca.x += w0.x; ca.y += w0.y;
            }
            C[mv - 1].x += ca.x + cb.x;
            C[mv - 1].y += ca.y + cb.y;
        }

        // write prefetched chunk c+1 into the other buffer
        if (c + 1 < NCHUNK) {
            float4* lb = (float4*)(smem + ((c + 1) & 1) * CHUNK_F);
            lb[0 * 256 + tid] = rg0;
            lb[1 * 256 + tid] = rg1;
            lb[2 * 256 + tid] = rg2;
            lb[3 * 256 + tid] = rg3;
        }
        __syncthreads();
    }

    // ---- persistent membrane state ----
    float2 t0 = ((const float2*)(ws + B0_OFF))[lane];   // neurons 2*lane, 2*lane+1
    float2 t1 = ((const float2*)(ws + B1_OFF))[lane];
    float2 t2 = ((const float2*)(ws + B2_OFF))[lane];
    float4 t3[4], cnt[4];                               // elems r*256 + 4*lane + c
    {
        const float4* b3v = (const float4*)(ws + B3_OFF);
#pragma unroll
        for (int r = 0; r < 3; ++r) t3[r] = b3v[r * 64 + lane];
        t3[3] = make_float4(0.f, 0.f, 0.f, 0.f);
        if (lane < 4) t3[3] = b3v[192 + lane];
#pragma unroll
        for (int r = 0; r < 4; ++r) cnt[r] = make_float4(0.f, 0.f, 0.f, 0.f);
    }

    for (int s = 1; s <= NSTEP; ++s) {
        // ---- input current: sum of active bucket vectors (register-only) ----
#pragma unroll
        for (int mv = 1; mv <= 16; ++mv) {
            if (((s * mv) & 15) < mv) { t0.x += C[mv - 1].x; t0.y += C[mv - 1].y; }
        }
        // ---- layer0 spikes -> layer1 ----
        {
            bool px = (t0.x >= 1.0f), py = (t0.y >= 1.0f);
            unsigned long long mx = __ballot(px);
            unsigned long long my = __ballot(py);
            if (px) t0.x -= 1.0f;
            if (py) t0.y -= 1.0f;
            while (mx) {
                int b = __builtin_ctzll(mx); mx &= mx - 1;
                const float2* colp = (const float2*)(W1t + (2 * b) * HID);
                float2 w = colp[lane]; t1.x += w.x; t1.y += w.y;
            }
            while (my) {
                int b = __builtin_ctzll(my); my &= my - 1;
                const float2* colp = (const float2*)(W1t + (2 * b + 1) * HID);
                float2 w = colp[lane]; t1.x += w.x; t1.y += w.y;
            }
        }
        // ---- layer1 spikes -> layer2 ----
        {
            bool px = (t1.x >= 1.0f), py = (t1.y >= 1.0f);
            unsigned long long mx = __ballot(px);
            unsigned long long my = __ballot(py);
            if (px) t1.x -= 1.0f;
            if (py) t1.y -= 1.0f;
            while (mx) {
                int b = __builtin_ctzll(mx); mx &= mx - 1;
                const float2* colp = (const float2*)(W2t + (2 * b) * HID);
                float2 w = colp[lane]; t2.x += w.x; t2.y += w.y;
            }
            while (my) {
                int b = __builtin_ctzll(my); my &= my - 1;
                const float2* colp = (const float2*)(W2t + (2 * b + 1) * HID);
                float2 w = colp[lane]; t2.x += w.x; t2.y += w.y;
            }
        }
        // ---- layer2 spikes -> layer3 ----
        {
            bool px = (t2.x >= 1.0f), py = (t2.y >= 1.0f);
            unsigned long long mx = __ballot(px);
            unsigned long long my = __ballot(py);
            if (px) t2.x -= 1.0f;
            if (py) t2.y -= 1.0f;
            while (mx) {
                int b = __builtin_ctzll(mx); mx &= mx - 1;
                const float4* colp = (const float4*)(W3t + (2 * b) * IN_DIM);
#pragma unroll
                for (int r = 0; r < 3; ++r) {
                    float4 w = colp[r * 64 + lane];
                    t3[r].x += w.x; t3[r].y += w.y; t3[r].z += w.z; t3[r].w += w.w;
                }
                if (lane < 4) {
                    float4 w = colp[192 + lane];
                    t3[3].x += w.x; t3[3].y += w.y; t3[3].z += w.z; t3[3].w += w.w;
                }
            }
            while (my) {
                int b = __builtin_ctzll(my); my &= my - 1;
                const float4* colp = (const float4*)(W3t + (2 * b + 1) * IN_DIM);
#pragma unroll
                for (int r = 0; r < 3; ++r) {
                    float4 w = colp[r * 64 + lane];
                    t3[r].x += w.x; t3[r].y += w.y; t3[r].z += w.z; t3[r].w += w.w;
                }
                if (lane < 4) {
                    float4 w = colp[192 + lane];
                    t3[3].x += w.x; t3[3].y += w.y; t3[3].z += w.z; t3[3].w += w.w;
                }
            }
        }
        // ---- layer3 spike + output count ----
#pragma unroll
        for (int r = 0; r < 4; ++r) {
            if (t3[r].x >= 1.0f) { t3[r].x -= 1.0f; cnt[r].x += 1.0f; }
            if (t3[r].y >= 1.0f) { t3[r].y -= 1.0f; cnt[r].y += 1.0f; }
            if (t3[r].z >= 1.0f) { t3[r].z -= 1.0f; cnt[r].z += 1.0f; }
            if (t3[r].w >= 1.0f) { t3[r].w -= 1.0f; cnt[r].w += 1.0f; }
        }
    }

    // ---- reconstruct: spikes * h_out3 ----
    const float h = ob3[1] - ob3[0];
    float4* orow = (float4*)(out + (size_t)sample * IN_DIM);
#pragma unroll
    for (int r = 0; r < 3; ++r)
        orow[r * 64 + lane] = make_float4(cnt[r].x * h, cnt[r].y * h, cnt[r].z * h, cnt[r].w * h);
    if (lane < 4)
        orow[192 + lane] = make_float4(cnt[3].x * h, cnt[3].y * h, cnt[3].z * h, cnt[3].w * h);
}

extern "C" void kernel_launch(void* const* d_in, const int* in_sizes, int n_in,
                              void* d_out, int out_size, void* d_ws, size_t ws_size,
                              hipStream_t stream)
{
    const float* feat = (const float*)d_in[0];
    const float* W0  = (const float*)d_in[1];
    const float* b0  = (const float*)d_in[2];
    const float* W1  = (const float*)d_in[3];
    const float* b1  = (const float*)d_in[4];
    const float* W2  = (const float*)d_in[5];
    const float* b2  = (const float*)d_in[6];
    const float* W3  = (const float*)d_in[7];
    const float* b3  = (const float*)d_in[8];
    const float* ib0 = (const float*)d_in[9];
    const float* ob0 = (const float*)d_in[10];
    const float* ib1 = (const float*)d_in[11];
    const float* ob1 = (const float*)d_in[12];
    const float* ib2 = (const float*)d_in[13];
    const float* ob2 = (const float*)d_in[14];
    const float* ib3 = (const float*)d_in[15];
    const float* ob3 = (const float*)d_in[16];
    float* ws  = (float*)d_ws;
    float* op  = (float*)d_out;

    prep_kernel<<<(WS_FLOATS + 255) / 256, 256, 0, stream>>>(
        W0, b0, W1, b1, W2, b2, W3, b3,
        ib0, ob0, ib1, ob1, ib2, ob2, ib3, ob3, ws);

    snn_main<<<BATCH / 4, 256, 0, stream>>>(feat, ws, ib0, ob3, op);
}

// Round 4
// 409.390 us; speedup vs baseline: 8.2584x; 1.0671x over previous
//
#include <hip/hip_runtime.h>

#define IN_DIM 784
#define HID 128
#define NSTEP 16
#define BATCH 16384

// ws float layout (all fp32):
constexpr int W0T_OFF = 0;                    // W0t[k*128+j] = W0[j][k]*r0   (784x128)
constexpr int W1T_OFF = W0T_OFF + IN_DIM*HID; // 100352: W1t (128x128)
constexpr int W2T_OFF = W1T_OFF + HID*HID;    // 116736: W2t (128x128)
constexpr int W3T_OFF = W2T_OFF + HID*HID;    // 133120: W3t[k*784+o] = W3[o][k]*r3 (128x784)
constexpr int B0_OFF  = W3T_OFF + HID*IN_DIM; // 233472
constexpr int B1_OFF  = B0_OFF + HID;
constexpr int B2_OFF  = B1_OFF + HID;
constexpr int B3_OFF  = B2_OFF + HID;
constexpr int WS_FLOATS = B3_OFF + IN_DIM;    // 234640 floats = 938 KB

// chunking of W0t for LDS staging
constexpr int CHUNK_COLS = 32;                // 32 cols x 128 floats = 16 KB
constexpr int CHUNK_F    = CHUNK_COLS * HID;  // 4096 floats
constexpr int NCHUNK     = 25;                // 24 full + 1 half (cols 768..783)

__global__ __launch_bounds__(256) void prep_kernel(
    const float* __restrict__ W0, const float* __restrict__ b0,
    const float* __restrict__ W1, const float* __restrict__ b1,
    const float* __restrict__ W2, const float* __restrict__ b2,
    const float* __restrict__ W3, const float* __restrict__ b3,
    const float* __restrict__ ib0, const float* __restrict__ ob0,
    const float* __restrict__ ib1, const float* __restrict__ ob1,
    const float* __restrict__ ib2, const float* __restrict__ ob2,
    const float* __restrict__ ib3, const float* __restrict__ ob3,
    float* __restrict__ ws)
{
    int idx = blockIdx.x * 256 + threadIdx.x;
    if (idx >= WS_FLOATS) return;
    float r0 = (ib0[1] - ib0[0]) / (ob0[1] - ob0[0]);
    float r1 = (ib1[1] - ib1[0]) / (ob1[1] - ob1[0]);
    float r2 = (ib2[1] - ib2[0]) / (ob2[1] - ob2[0]);
    float r3 = (ib3[1] - ib3[0]) / (ob3[1] - ob3[0]);
    if (idx < W1T_OFF) {
        int t = idx;            int k = t >> 7, j = t & 127;
        ws[idx] = W0[j * IN_DIM + k] * r0;
    } else if (idx < W2T_OFF) {
        int t = idx - W1T_OFF;  int k = t >> 7, j = t & 127;
        ws[idx] = W1[j * HID + k] * r1;
    } else if (idx < W3T_OFF) {
        int t = idx - W2T_OFF;  int k = t >> 7, j = t & 127;
        ws[idx] = W2[j * HID + k] * r2;
    } else if (idx < B0_OFF) {
        int t = idx - W3T_OFF;  int k = t / IN_DIM, o = t % IN_DIM;
        ws[idx] = W3[o * HID + k] * r3;
    } else if (idx < B1_OFF) ws[idx] = b0[idx - B0_OFF] * r0;
    else if (idx < B2_OFF)   ws[idx] = b1[idx - B1_OFF] * r1;
    else if (idx < B3_OFF)   ws[idx] = b2[idx - B2_OFF] * r2;
    else                     ws[idx] = b3[idx - B3_OFF] * r3;
}

__global__ __launch_bounds__(256) void snn_main(
    const float* __restrict__ feat,
    const float* __restrict__ ws,
    const float* __restrict__ ib0,
    const float* __restrict__ ob3,
    float* __restrict__ out)
{
    __shared__ float smem[2 * CHUNK_F];       // 32 KB double buffer

    const int tid  = threadIdx.x;
    const int lane = tid & 63;
    const int wid  = tid >> 6;
    const int sample = blockIdx.x * 4 + wid;

    const float* W0t = ws + W0T_OFF;
    const float* W1t = ws + W1T_OFF;
    const float* W2t = ws + W2T_OFF;
    const float* W3t = ws + W3T_OFF;
    const float* frow = feat + (size_t)sample * IN_DIM;

    float edge[16];
#pragma unroll
    for (int e = 0; e < 16; ++e) edge[e] = ib0[e + 1];

    // ---- stage chunk 0 ----
    {
        const float4* g4 = (const float4*)W0t;
        float4* lb = (float4*)smem;
#pragma unroll
        for (int i = 0; i < 4; ++i) lb[i * 256 + tid] = g4[i * 256 + tid];
    }
    __syncthreads();

    // ---- bucket build: C[mv-1] = sum of W0t columns whose pixel level == mv ----
    float2 C[16];
#pragma unroll
    for (int mv = 0; mv < 16; ++mv) C[mv] = make_float2(0.f, 0.f);

    for (int c = 0; c < NCHUNK; ++c) {
        // prefetch next chunk into registers (issued early; overlaps consume).
        float4 rg0, rg1, rg2, rg3;
        {
            const float4* g4 = (const float4*)W0t + (size_t)(c + 1) * (CHUNK_F / 4);
            rg0 = g4[0 * 256 + tid];
            rg1 = g4[1 * 256 + tid];
            rg2 = g4[2 * 256 + tid];
            rg3 = g4[3 * 256 + tid];
        }

        // digitize this chunk's 32 columns (lanes 32-63 duplicate lanes 0-31)
        int col = c * CHUNK_COLS + (lane & 31);
        bool valid = col < IN_DIM;
        float x = frow[valid ? col : 0];
        int mm = 0;
#pragma unroll
        for (int e = 0; e < 16; ++e) mm += (x >= edge[e]) ? 1 : 0;
        if (!valid) mm = -1;

        // consume chunk c from LDS (4-peeled, 2 acc chains)
        const float2* bufp = (const float2*)(smem + (c & 1) * CHUNK_F);
#pragma unroll
        for (int mv = 1; mv <= 16; ++mv) {
            unsigned mk = (unsigned)__ballot(mm == mv);
            float2 ca = make_float2(0.f, 0.f), cb = make_float2(0.f, 0.f);
            while (mk) {
                int b0 = __builtin_ctz(mk); mk &= mk - 1;
                float2 w0 = bufp[b0 * 64 + lane];
                if (mk) {
                    int b1 = __builtin_ctz(mk); mk &= mk - 1;
                    float2 w1 = bufp[b1 * 64 + lane];
                    if (mk) {
                        int b2 = __builtin_ctz(mk); mk &= mk - 1;
                        float2 w2 = bufp[b2 * 64 + lane];
                        if (mk) {
                            int b3i = __builtin_ctz(mk); mk &= mk - 1;
                            float2 w3 = bufp[b3i * 64 + lane];
                            cb.x += w3.x; cb.y += w3.y;
                        }
                        ca.x += w2.x; ca.y += w2.y;
                    }
                    cb.x += w1.x; cb.y += w1.y;
                }
                ca.x += w0.x; ca.y += w0.y;
            }
            C[mv - 1].x += ca.x + cb.x;
            C[mv - 1].y += ca.y + cb.y;
        }

        if (c + 1 < NCHUNK) {
            float4* lb = (float4*)(smem + ((c + 1) & 1) * CHUNK_F);
            lb[0 * 256 + tid] = rg0;
            lb[1 * 256 + tid] = rg1;
            lb[2 * 256 + tid] = rg2;
            lb[3 * 256 + tid] = rg3;
        }
        __syncthreads();
    }

    // ---- persistent membrane state ----
    float2 t0 = ((const float2*)(ws + B0_OFF))[lane];
    float2 t1 = ((const float2*)(ws + B1_OFF))[lane];
    float2 t2 = ((const float2*)(ws + B2_OFF))[lane];
    float4 t3[4], cnt[4];
    {
        const float4* b3v = (const float4*)(ws + B3_OFF);
#pragma unroll
        for (int r = 0; r < 3; ++r) t3[r] = b3v[r * 64 + lane];
        t3[3] = make_float4(0.f, 0.f, 0.f, 0.f);
        if (lane < 4) t3[3] = b3v[192 + lane];
#pragma unroll
        for (int r = 0; r < 4; ++r) cnt[r] = make_float4(0.f, 0.f, 0.f, 0.f);
    }

    for (int s = 1; s <= NSTEP; ++s) {
        // ---- input current: sum of active bucket vectors (register-only) ----
#pragma unroll
        for (int mv = 1; mv <= 16; ++mv) {
            if (((s * mv) & 15) < mv) { t0.x += C[mv - 1].x; t0.y += C[mv - 1].y; }
        }
        // ---- layer0 spikes -> layer1 (4-peeled: 4 loads in flight) ----
        {
            bool px = (t0.x >= 1.0f), py = (t0.y >= 1.0f);
            unsigned long long mx = __ballot(px);
            unsigned long long my = __ballot(py);
            if (px) t0.x -= 1.0f;
            if (py) t0.y -= 1.0f;
            float2 ca = make_float2(0.f, 0.f), cb = make_float2(0.f, 0.f);
            while (mx) {
                int b0 = __builtin_ctzll(mx); mx &= mx - 1;
                float2 w0 = ((const float2*)(W1t + (2 * b0) * HID))[lane];
                if (mx) {
                    int b1 = __builtin_ctzll(mx); mx &= mx - 1;
                    float2 w1 = ((const float2*)(W1t + (2 * b1) * HID))[lane];
                    if (mx) {
                        int b2 = __builtin_ctzll(mx); mx &= mx - 1;
                        float2 w2 = ((const float2*)(W1t + (2 * b2) * HID))[lane];
                        if (mx) {
                            int b3i = __builtin_ctzll(mx); mx &= mx - 1;
                            float2 w3 = ((const float2*)(W1t + (2 * b3i) * HID))[lane];
                            cb.x += w3.x; cb.y += w3.y;
                        }
                        ca.x += w2.x; ca.y += w2.y;
                    }
                    cb.x += w1.x; cb.y += w1.y;
                }
                ca.x += w0.x; ca.y += w0.y;
            }
            while (my) {
                int b0 = __builtin_ctzll(my); my &= my - 1;
                float2 w0 = ((const float2*)(W1t + (2 * b0 + 1) * HID))[lane];
                if (my) {
                    int b1 = __builtin_ctzll(my); my &= my - 1;
                    float2 w1 = ((const float2*)(W1t + (2 * b1 + 1) * HID))[lane];
                    if (my) {
                        int b2 = __builtin_ctzll(my); my &= my - 1;
                        float2 w2 = ((const float2*)(W1t + (2 * b2 + 1) * HID))[lane];
                        if (my) {
                            int b3i = __builtin_ctzll(my); my &= my - 1;
                            float2 w3 = ((const float2*)(W1t + (2 * b3i + 1) * HID))[lane];
                            cb.x += w3.x; cb.y += w3.y;
                        }
                        ca.x += w2.x; ca.y += w2.y;
                    }
                    cb.x += w1.x; cb.y += w1.y;
                }
                ca.x += w0.x; ca.y += w0.y;
            }
            t1.x += ca.x + cb.x; t1.y += ca.y + cb.y;
        }
        // ---- layer1 spikes -> layer2 (4-peeled) ----
        {
            bool px = (t1.x >= 1.0f), py = (t1.y >= 1.0f);
            unsigned long long mx = __ballot(px);
            unsigned long long my = __ballot(py);
            if (px) t1.x -= 1.0f;
            if (py) t1.y -= 1.0f;
            float2 ca = make_float2(0.f, 0.f), cb = make_float2(0.f, 0.f);
            while (mx) {
                int b0 = __builtin_ctzll(mx); mx &= mx - 1;
                float2 w0 = ((const float2*)(W2t + (2 * b0) * HID))[lane];
                if (mx) {
                    int b1 = __builtin_ctzll(mx); mx &= mx - 1;
                    float2 w1 = ((const float2*)(W2t + (2 * b1) * HID))[lane];
                    if (mx) {
                        int b2 = __builtin_ctzll(mx); mx &= mx - 1;
                        float2 w2 = ((const float2*)(W2t + (2 * b2) * HID))[lane];
                        if (mx) {
                            int b3i = __builtin_ctzll(mx); mx &= mx - 1;
                            float2 w3 = ((const float2*)(W2t + (2 * b3i) * HID))[lane];
                            cb.x += w3.x; cb.y += w3.y;
                        }
                        ca.x += w2.x; ca.y += w2.y;
                    }
                    cb.x += w1.x; cb.y += w1.y;
                }
                ca.x += w0.x; ca.y += w0.y;
            }
            while (my) {
                int b0 = __builtin_ctzll(my); my &= my - 1;
                float2 w0 = ((const float2*)(W2t + (2 * b0 + 1) * HID))[lane];
                if (my) {
                    int b1 = __builtin_ctzll(my); my &= my - 1;
                    float2 w1 = ((const float2*)(W2t + (2 * b1 + 1) * HID))[lane];
                    if (my) {
                        int b2 = __builtin_ctzll(my); my &= my - 1;
                        float2 w2 = ((const float2*)(W2t + (2 * b2 + 1) * HID))[lane];
                        if (my) {
                            int b3i = __builtin_ctzll(my); my &= my - 1;
                            float2 w3 = ((const float2*)(W2t + (2 * b3i + 1) * HID))[lane];
                            cb.x += w3.x; cb.y += w3.y;
                        }
                        ca.x += w2.x; ca.y += w2.y;
                    }
                    cb.x += w1.x; cb.y += w1.y;
                }
                ca.x += w0.x; ca.y += w0.y;
            }
            t2.x += ca.x + cb.x; t2.y += ca.y + cb.y;
        }
        // ---- layer2 spikes -> layer3 (2-peeled spikes x 4-wide loads) ----
        {
            bool px = (t2.x >= 1.0f), py = (t2.y >= 1.0f);
            unsigned long long mx = __ballot(px);
            unsigned long long my = __ballot(py);
            if (px) t2.x -= 1.0f;
            if (py) t2.y -= 1.0f;
            while (mx) {
                int b0 = __builtin_ctzll(mx); mx &= mx - 1;
                const float4* c0 = (const float4*)(W3t + (2 * b0) * IN_DIM);
                float4 x0 = c0[lane], x1 = c0[64 + lane], x2 = c0[128 + lane];
                float4 x3 = c0[192 + (lane & 3)];
                if (mx) {
                    int b1 = __builtin_ctzll(mx); mx &= mx - 1;
                    const float4* c1 = (const float4*)(W3t + (2 * b1) * IN_DIM);
                    float4 y0 = c1[lane], y1 = c1[64 + lane], y2 = c1[128 + lane];
                    float4 y3 = c1[192 + (lane & 3)];
                    t3[0].x += y0.x; t3[0].y += y0.y; t3[0].z += y0.z; t3[0].w += y0.w;
                    t3[1].x += y1.x; t3[1].y += y1.y; t3[1].z += y1.z; t3[1].w += y1.w;
                    t3[2].x += y2.x; t3[2].y += y2.y; t3[2].z += y2.z; t3[2].w += y2.w;
                    if (lane < 4) { t3[3].x += y3.x; t3[3].y += y3.y; t3[3].z += y3.z; t3[3].w += y3.w; }
                }
                t3[0].x += x0.x; t3[0].y += x0.y; t3[0].z += x0.z; t3[0].w += x0.w;
                t3[1].x += x1.x; t3[1].y += x1.y; t3[1].z += x1.z; t3[1].w += x1.w;
                t3[2].x += x2.x; t3[2].y += x2.y; t3[2].z += x2.z; t3[2].w += x2.w;
                if (lane < 4) { t3[3].x += x3.x; t3[3].y += x3.y; t3[3].z += x3.z; t3[3].w += x3.w; }
            }
            while (my) {
                int b0 = __builtin_ctzll(my); my &= my - 1;
                const float4* c0 = (const float4*)(W3t + (2 * b0 + 1) * IN_DIM);
                float4 x0 = c0[lane], x1 = c0[64 + lane], x2 = c0[128 + lane];
                float4 x3 = c0[192 + (lane & 3)];
                if (my) {
                    int b1 = __builtin_ctzll(my); my &= my - 1;
                    const float4* c1 = (const float4*)(W3t + (2 * b1 + 1) * IN_DIM);
                    float4 y0 = c1[lane], y1 = c1[64 + lane], y2 = c1[128 + lane];
                    float4 y3 = c1[192 + (lane & 3)];
                    t3[0].x += y0.x; t3[0].y += y0.y; t3[0].z += y0.z; t3[0].w += y0.w;
                    t3[1].x += y1.x; t3[1].y += y1.y; t3[1].z += y1.z; t3[1].w += y1.w;
                    t3[2].x += y2.x; t3[2].y += y2.y; t3[2].z += y2.z; t3[2].w += y2.w;
                    if (lane < 4) { t3[3].x += y3.x; t3[3].y += y3.y; t3[3].z += y3.z; t3[3].w += y3.w; }
                }
                t3[0].x += x0.x; t3[0].y += x0.y; t3[0].z += x0.z; t3[0].w += x0.w;
                t3[1].x += x1.x; t3[1].y += x1.y; t3[1].z += x1.z; t3[1].w += x1.w;
                t3[2].x += x2.x; t3[2].y += x2.y; t3[2].z += x2.z; t3[2].w += x2.w;
                if (lane < 4) { t3[3].x += x3.x; t3[3].y += x3.y; t3[3].z += x3.z; t3[3].w += x3.w; }
            }
        }
        // ---- layer3 spike + output count ----
#pragma unroll
        for (int r = 0; r < 4; ++r) {
            if (t3[r].x >= 1.0f) { t3[r].x -= 1.0f; cnt[r].x += 1.0f; }
            if (t3[r].y >= 1.0f) { t3[r].y -= 1.0f; cnt[r].y += 1.0f; }
            if (t3[r].z >= 1.0f) { t3[r].z -= 1.0f; cnt[r].z += 1.0f; }
            if (t3[r].w >= 1.0f) { t3[r].w -= 1.0f; cnt[r].w += 1.0f; }
        }
    }

    // ---- reconstruct: spikes * h_out3 ----
    const float h = ob3[1] - ob3[0];
    float4* orow = (float4*)(out + (size_t)sample * IN_DIM);
#pragma unroll
    for (int r = 0; r < 3; ++r)
        orow[r * 64 + lane] = make_float4(cnt[r].x * h, cnt[r].y * h, cnt[r].z * h, cnt[r].w * h);
    if (lane < 4)
        orow[192 + lane] = make_float4(cnt[3].x * h, cnt[3].y * h, cnt[3].z * h, cnt[3].w * h);
}

extern "C" void kernel_launch(void* const* d_in, const int* in_sizes, int n_in,
                              void* d_out, int out_size, void* d_ws, size_t ws_size,
                              hipStream_t stream)
{
    const float* feat = (const float*)d_in[0];
    const float* W0  = (const float*)d_in[1];
    const float* b0  = (const float*)d_in[2];
    const float* W1  = (const float*)d_in[3];
    const float* b1  = (const float*)d_in[4];
    const float* W2  = (const float*)d_in[5];
    const float* b2  = (const float*)d_in[6];
    const float* W3  = (const float*)d_in[7];
    const float* b3  = (const float*)d_in[8];
    const float* ib0 = (const float*)d_in[9];
    const float* ob0 = (const float*)d_in[10];
    const float* ib1 = (const float*)d_in[11];
    const float* ob1 = (const float*)d_in[12];
    const float* ib2 = (const float*)d_in[13];
    const float* ob2 = (const float*)d_in[14];
    const float* ib3 = (const float*)d_in[15];
    const float* ob3 = (const float*)d_in[16];
    float* ws  = (float*)d_ws;
    float* op  = (float*)d_out;

    prep_kernel<<<(WS_FLOATS + 255) / 256, 256, 0, stream>>>(
        W0, b0, W1, b1, W2, b2, W3, b3,
        ib0, ob0, ib1, ob1, ib2, ob2, ib3, ob3, ws);

    snn_main<<<BATCH / 4, 256, 0, stream>>>(feat, ws, ib0, ob3, op);
}